// Round 16
// baseline (141.786 us; speedup 1.0000x reference)
//
#include <hip/hip_runtime.h>
#include <math.h>

#define BB 2
#define CC 272
#define GG 17
#define CG 16
#define HH 128
#define WW 128
#define HWX (HH*WW)
#define AFFC 102   // 6*G
#define NSLAB (BB*GG)          // 34
#define TILES_PER_SLAB 64      // (128/16)^2
#define NWG (NSLAB*TILES_PER_SLAB)  // 2176 = 8*272
#define WGPX (NWG/8)           // 272 per XCD
#define PSTR ((size_t)NSLAB*HWX*4)  // u32 stride between the two 8-ch planes

typedef float f4nt __attribute__((ext_vector_type(4)));     // NT-compatible vec4
typedef unsigned u4nt __attribute__((ext_vector_type(4)));  // NT-compatible uvec4
typedef _Float16 h2 __attribute__((ext_vector_type(2)));    // packed half2

__device__ __forceinline__ h2 bch(unsigned u) { return __builtin_bit_cast(h2, u); }
__device__ __forceinline__ unsigned hpk(float a, float b) {
    return __builtin_bit_cast(unsigned, __builtin_amdgcn_cvt_pkrtz(a, b));
}
__device__ __forceinline__ h2 hbc(float a) {
    return __builtin_bit_cast(h2, __builtin_amdgcn_cvt_pkrtz(a, a));
}

#if __has_builtin(__builtin_amdgcn_fdot2)
#define FDOT2(A, B, C) __builtin_amdgcn_fdot2((A), (B), (C), false)
#else
#define FDOT2(A, B, C) fmaf((float)(A).x, (float)(B).x, fmaf((float)(A).y, (float)(B).y, (C)))
#endif

// bf16 helpers (pre-BN staging stays bf16)
__device__ __forceinline__ unsigned f2bf(float f) {
    unsigned u = __float_as_uint(f);
    return (u + 0x7fffu + ((u >> 16) & 1u)) >> 16;
}
__device__ __forceinline__ float bflo(unsigned u) { return __uint_as_float(u << 16); }
__device__ __forceinline__ float bfhi(unsigned u) { return __uint_as_float(u & 0xffff0000u); }

// ---------------- Kernel W: weight re-layouts to packed half2 ---------------
__global__ __launch_bounds__(256) void wt_kernel(
    const float* __restrict__ dc_w, const float* __restrict__ tm_w,
    unsigned* __restrict__ dc_wh, unsigned* __restrict__ tm_wh)
{
    int i = blockIdx.x * 256 + threadIdx.x;
    if (i < GG * 8 * 9 * CG) {           // 19584
        int oc = i & 15, t = (i >> 4) % 9, cp = (i / 144) % 8, g = i / 1152;
        float w0 = dc_w[((size_t)(g * 16 + oc) * 16 + 2 * cp) * 9 + t];
        float w1 = dc_w[((size_t)(g * 16 + oc) * 16 + 2 * cp + 1) * 9 + t];
        dc_wh[i] = hpk(w0, w1);
    }
    if (i < GG * 6 * 9 * 8) {            // 7344
        int cp = i & 7, t = (i >> 3) % 9, j = (i / 72) % 6, ig = i / 432;
        float w0 = tm_w[((size_t)(ig * 6 + j) * 16 + 2 * cp) * 9 + t];
        float w1 = tm_w[((size_t)(ig * 6 + j) * 16 + 2 * cp + 1) * 9 + t];
        tm_wh[i] = hpk(w0, w1);
    }
}

// ------- Kernel T: NCHW -> two 8-channel planes, f16, 16B/px per plane ------
__global__ __launch_bounds__(256) void transpose_kernel(
    const float* __restrict__ x, unsigned* __restrict__ xt)
{
    __shared__ float tile[CG][WW + 1];
    const int h = blockIdx.x & (HH - 1);
    const int g = (blockIdx.x >> 7) % GG;
    const int b = blockIdx.x / (GG * HH);
    const int tid = threadIdx.x;
    const float* src = x + (size_t)(b * CC + g * CG) * HWX + h * WW;
    for (int i = tid; i < CG * WW; i += 256) {
        int c = i >> 7, w = i & (WW - 1);
        tile[c][w] = src[(size_t)c * HWX + w];
    }
    __syncthreads();
    const size_t rowbase = ((size_t)(b * GG + g) * HWX + h * WW) * 4;
    unsigned* d0 = xt + rowbase;          // plane0
    unsigned* d1 = xt + PSTR + rowbase;   // plane1
    for (int i = tid; i < 4 * WW; i += 256) {
        int w = i >> 2, c4 = i & 3;       // u32 c4 of px w
        d0[(size_t)w * 4 + c4] = hpk(tile[2 * c4][w],     tile[2 * c4 + 1][w]);
        d1[(size_t)w * 4 + c4] = hpk(tile[8 + 2 * c4][w], tile[8 + 2 * c4 + 1][w]);
    }
}

// ---------------- Kernel A: grouped 3x3 offset-transform conv ----------------
// unroll 3: one kernel-row of taps staged (6 uint4) -- pipelines loads without
// the full-unroll VGPR blowup (R11 lesson).
__global__ __launch_bounds__(256) void aff_conv_kernel(
    const unsigned* __restrict__ xt, const unsigned* __restrict__ tm_wh,
    const float* __restrict__ tm_b, float* __restrict__ aff)
{
    const int ig = blockIdx.y;
    const int b = blockIdx.z;
    const int tid = threadIdx.x;

    const int p = blockIdx.x * 256 + tid;
    const int h = p >> 7, w = p & (WW - 1);
    const unsigned* xb0 = xt + (size_t)(b * GG + ig) * HWX * 4;
    const unsigned* xb1 = xb0 + PSTR;
    const unsigned* wbh = tm_wh + (size_t)ig * (6 * 9 * 8);   // [j][t][cp]

    float acc[6];
#pragma unroll
    for (int j = 0; j < 6; ++j) acc[j] = 0.f;

#pragma unroll 3
    for (int t = 0; t < 9; ++t) {
        int hy = h + t / 3 - 1;
        int wx = w + t % 3 - 1;
        uint4 u0 = {0, 0, 0, 0}, u1 = {0, 0, 0, 0};
        if (hy >= 0 && hy < HH && wx >= 0 && wx < WW) {
            u0 = *(const uint4*)(xb0 + (size_t)(hy * WW + wx) * 4);
            u1 = *(const uint4*)(xb1 + (size_t)(hy * WW + wx) * 4);
        }
#pragma unroll
        for (int j = 0; j < 6; ++j) {
            const uint4* wp = (const uint4*)(wbh + (j * 9 + t) * 8);  // uniform -> s_load
            uint4 qa = wp[0], qb = wp[1];
            float a = acc[j];
            a = FDOT2(bch(u0.x), bch(qa.x), a); a = FDOT2(bch(u0.y), bch(qa.y), a);
            a = FDOT2(bch(u0.z), bch(qa.z), a); a = FDOT2(bch(u0.w), bch(qa.w), a);
            a = FDOT2(bch(u1.x), bch(qb.x), a); a = FDOT2(bch(u1.y), bch(qb.y), a);
            a = FDOT2(bch(u1.z), bch(qb.z), a); a = FDOT2(bch(u1.w), bch(qb.w), a);
            acc[j] = a;
        }
    }
#pragma unroll
    for (int j = 0; j < 6; ++j)
        aff[(size_t)(b * AFFC + ig * 6 + j) * HWX + p] = acc[j] + tm_b[ig * 6 + j];
}

// ---------------- Kernel C: deformable grouped conv + BN-stat partials -------
// 1D grid, XCD-chunked; two-plane f16 xt; packed-half2 bilinear; fdot2 MAC.
// NO launch_bounds: compiler keeps natural VGPR (~40-64, no forced fit -> no
// spill) and hardware fills up to 8 blocks/CU. (256,8) FORCES VGPR 32 -> spill
// catastrophe (R10). (256,6) caps residency at 6 and observed ~3.5 (R14).
// L2 window at 8 blocks/CU: 256 blocks/XCD ~ 4 slabs x 0.5MB = 2MB < 4MiB. OK.

#define MACC(T, CP, S2) { \
    const uint4* wp_ = (const uint4*)(wgh + ((CP) * 9 + (T)) * CG); \
    uint4 q0 = wp_[0], q1 = wp_[1], q2 = wp_[2], q3 = wp_[3]; \
    acc[0]  = FDOT2(S2, bch(q0.x), acc[0]);  acc[1]  = FDOT2(S2, bch(q0.y), acc[1]); \
    acc[2]  = FDOT2(S2, bch(q0.z), acc[2]);  acc[3]  = FDOT2(S2, bch(q0.w), acc[3]); \
    acc[4]  = FDOT2(S2, bch(q1.x), acc[4]);  acc[5]  = FDOT2(S2, bch(q1.y), acc[5]); \
    acc[6]  = FDOT2(S2, bch(q1.z), acc[6]);  acc[7]  = FDOT2(S2, bch(q1.w), acc[7]); \
    acc[8]  = FDOT2(S2, bch(q2.x), acc[8]);  acc[9]  = FDOT2(S2, bch(q2.y), acc[9]); \
    acc[10] = FDOT2(S2, bch(q2.z), acc[10]); acc[11] = FDOT2(S2, bch(q2.w), acc[11]); \
    acc[12] = FDOT2(S2, bch(q3.x), acc[12]); acc[13] = FDOT2(S2, bch(q3.y), acc[13]); \
    acc[14] = FDOT2(S2, bch(q3.z), acc[14]); acc[15] = FDOT2(S2, bch(q3.w), acc[15]); }

#define SEM(T, CP, UA, UB, UC, UD) { \
    h2 s2 = bch(UA) * W00 + bch(UB) * W01 + bch(UC) * W10 + bch(UD) * W11; \
    MACC(T, CP, s2) }

#define TAP(T, I0, K0, I1, K1) { \
    float dy = ((I0) ? a10 : a00) * (float)((K0) / 3 - 1) \
             + ((I0) ? a11 : a01) * (float)((K0) % 3 - 1) + ((I0) ? a12 : a02); \
    float dx = ((I1) ? a10 : a00) * (float)((K1) / 3 - 1) \
             + ((I1) ? a11 : a01) * (float)((K1) % 3 - 1) + ((I1) ? a12 : a02); \
    float py = (float)(h + (T) / 3 - 1) + dy; \
    float px = (float)(w + (T) % 3 - 1) + dx; \
    float y0f = floorf(py), x0f = floorf(px); \
    float wy = py - y0f, wx = px - x0f; \
    int y0 = (int)y0f, x0 = (int)x0f; \
    int y1 = y0 + 1, x1 = x0 + 1; \
    bool vy0 = (y0 >= 0) && (y0 < HH), vy1 = (y1 >= 0) && (y1 < HH); \
    bool vx0 = (x0 >= 0) && (x0 < WW), vx1 = (x1 >= 0) && (x1 < WW); \
    int y0c = min(max(y0, 0), HH - 1), y1c = min(max(y1, 0), HH - 1); \
    int x0c = min(max(x0, 0), WW - 1), x1c = min(max(x1, 0), WW - 1); \
    float w00 = (vy0 && vx0) ? (1.f - wy) * (1.f - wx) : 0.f; \
    float w01 = (vy0 && vx1) ? (1.f - wy) * wx : 0.f; \
    float w10 = (vy1 && vx0) ? wy * (1.f - wx) : 0.f; \
    float w11 = (vy1 && vx1) ? wy * wx : 0.f; \
    h2 W00 = hbc(w00), W01 = hbc(w01), W10 = hbc(w10), W11 = hbc(w11); \
    int l00 = y0c * WW + x0c, l01 = y0c * WW + x1c; \
    int l10 = y1c * WW + x0c, l11 = y1c * WW + x1c; \
    uint4 A0 = *(const uint4*)(xb0 + (size_t)l00 * 4); \
    uint4 A1 = *(const uint4*)(xb1 + (size_t)l00 * 4); \
    uint4 B0 = *(const uint4*)(xb0 + (size_t)l01 * 4); \
    uint4 B1 = *(const uint4*)(xb1 + (size_t)l01 * 4); \
    uint4 C0 = *(const uint4*)(xb0 + (size_t)l10 * 4); \
    uint4 C1 = *(const uint4*)(xb1 + (size_t)l10 * 4); \
    uint4 D0 = *(const uint4*)(xb0 + (size_t)l11 * 4); \
    uint4 D1 = *(const uint4*)(xb1 + (size_t)l11 * 4); \
    SEM(T, 0, A0.x, B0.x, C0.x, D0.x) SEM(T, 1, A0.y, B0.y, C0.y, D0.y) \
    SEM(T, 2, A0.z, B0.z, C0.z, D0.z) SEM(T, 3, A0.w, B0.w, C0.w, D0.w) \
    SEM(T, 4, A1.x, B1.x, C1.x, D1.x) SEM(T, 5, A1.y, B1.y, C1.y, D1.y) \
    SEM(T, 6, A1.z, B1.z, C1.z, D1.z) SEM(T, 7, A1.w, B1.w, C1.w, D1.w) }

__global__ __launch_bounds__(256) void deform_kernel(
    const unsigned* __restrict__ xt, const unsigned* __restrict__ dc_wh,
    const float* __restrict__ aff_buf, unsigned* __restrict__ pre,
    float* __restrict__ stat_sum, float* __restrict__ stat_sqs)
{
    __shared__ float red[CG][4][2];

    const int bid = blockIdx.x;
    const int work = (bid & 7) * WGPX + (bid >> 3);
    const int slab = work / TILES_PER_SLAB;      // (b,g)
    const int tile = work % TILES_PER_SLAB;
    const int b = slab / GG;
    const int g = slab % GG;

    const int tid = threadIdx.y * 16 + threadIdx.x;
    const int h = (tile >> 3) * 16 + threadIdx.y;
    const int w = (tile & 7) * 16 + threadIdx.x;

    // 2x3 affine params (single-touch -> non-temporal); channel = 51*i+17*j+g
    const float* ab = aff_buf + (size_t)b * AFFC * HWX + h * WW + w;
    float a00 = __builtin_nontemporal_load(ab + (size_t)(0 * 51 + 0 * 17 + g) * HWX);
    float a01 = __builtin_nontemporal_load(ab + (size_t)(0 * 51 + 1 * 17 + g) * HWX);
    float a02 = __builtin_nontemporal_load(ab + (size_t)(0 * 51 + 2 * 17 + g) * HWX);
    float a10 = __builtin_nontemporal_load(ab + (size_t)(1 * 51 + 0 * 17 + g) * HWX);
    float a11 = __builtin_nontemporal_load(ab + (size_t)(1 * 51 + 1 * 17 + g) * HWX);
    float a12 = __builtin_nontemporal_load(ab + (size_t)(1 * 51 + 2 * 17 + g) * HWX);

    const unsigned* xb0 = xt + (size_t)(b * GG + g) * HWX * 4;
    const unsigned* xb1 = xb0 + PSTR;
    const unsigned* wgh = dc_wh + (size_t)g * (8 * 9 * CG);   // [cp][t][oc]

    float acc[CG];
#pragma unroll
    for (int oc = 0; oc < CG; ++oc) acc[oc] = 0.f;

    // flat e = i*9+k; tap t: e0=2t -> (I0,K0), e1=2t+1 -> (I1,K1)
    TAP(0, 0, 0, 0, 1)
    TAP(1, 0, 2, 0, 3)
    TAP(2, 0, 4, 0, 5)
    TAP(3, 0, 6, 0, 7)
    TAP(4, 0, 8, 1, 0)
    TAP(5, 1, 1, 1, 2)
    TAP(6, 1, 3, 1, 4)
    TAP(7, 1, 5, 1, 6)
    TAP(8, 1, 7, 1, 8)

    // pre as bf16 channel-last [slab][px][16]: lane writes 32B contiguous (NT)
    unsigned pk[8];
#pragma unroll
    for (int k = 0; k < 8; ++k)
        pk[k] = f2bf(acc[2 * k]) | (f2bf(acc[2 * k + 1]) << 16);
    {
        u4nt q0 = {pk[0], pk[1], pk[2], pk[3]};
        u4nt q1 = {pk[4], pk[5], pk[6], pk[7]};
        u4nt* pp = (u4nt*)(pre + ((size_t)slab * HWX + h * WW + w) * (CG / 2));
        __builtin_nontemporal_store(q0, pp);
        __builtin_nontemporal_store(q1, pp + 1);
    }

    // BN partial sums from exact f32 acc
    const int lane = tid & 63, wave = tid >> 6;
#pragma unroll
    for (int oc = 0; oc < CG; ++oc) {
        float s = acc[oc], q = acc[oc] * acc[oc];
#pragma unroll
        for (int off = 32; off > 0; off >>= 1) {
            s += __shfl_down(s, off);
            q += __shfl_down(q, off);
        }
        if (lane == 0) { red[oc][wave][0] = s; red[oc][wave][1] = q; }
    }
    __syncthreads();
    if (tid < CG) {
        float s = red[tid][0][0] + red[tid][1][0] + red[tid][2][0] + red[tid][3][0];
        float q = red[tid][0][1] + red[tid][1][1] + red[tid][2][1] + red[tid][3][1];
        int ch = g * CG + tid;
        atomicAdd(&stat_sum[ch], s);
        atomicAdd(&stat_sqs[ch], q);
    }
}

// ---------------- Kernel D: BN + residual ReLU (pre: bf16 channel-last) ------
__global__ __launch_bounds__(256) void bn_res_relu_kernel(
    const unsigned* __restrict__ pre, const float* __restrict__ x,
    const float* __restrict__ ssum, const float* __restrict__ ssqs,
    const float* __restrict__ gamma, const float* __restrict__ beta,
    float* __restrict__ out)
{
    const int blk = blockIdx.x;
    const int slab = blk >> 4;       // 16 chunks per slab
    const int chunk = blk & 15;
    const int b = slab / GG, g = slab % GG;
    const int px0 = chunk * 1024 + threadIdx.x * 4;

    const float n = (float)(BB * HWX);
    float sc[16], sh[16];
#pragma unroll
    for (int oc = 0; oc < 16; ++oc) {
        int ch = g * CG + oc;
        float mean = ssum[ch] / n;
        float var = ssqs[ch] / n - mean * mean;
        float s = rsqrtf(var + 1e-5f) * gamma[ch];
        sc[oc] = s;
        sh[oc] = fmaf(-mean, s, beta[ch]);
    }

    const uint4* pp = (const uint4*)(pre + ((size_t)slab * HWX + px0) * (CG / 2));
    unsigned Pu[32];
#pragma unroll
    for (int k = 0; k < 8; ++k) {
        uint4 v = pp[k];
        Pu[4 * k] = v.x; Pu[4 * k + 1] = v.y; Pu[4 * k + 2] = v.z; Pu[4 * k + 3] = v.w;
    }
    const float* xb = x + (size_t)(b * CC + g * CG) * HWX + px0;
    float* ob = out + (size_t)(b * CC + g * CG) * HWX + px0;

#pragma unroll
    for (int oc = 0; oc < 16; ++oc) {
        f4nt xv = __builtin_nontemporal_load((const f4nt*)(xb + (size_t)oc * HWX));
        f4nt r;
        float p0, p1, p2, p3;
        {
            unsigned u0 = Pu[0 * 8 + (oc >> 1)], u1 = Pu[1 * 8 + (oc >> 1)];
            unsigned u2 = Pu[2 * 8 + (oc >> 1)], u3 = Pu[3 * 8 + (oc >> 1)];
            p0 = (oc & 1) ? bfhi(u0) : bflo(u0);
            p1 = (oc & 1) ? bfhi(u1) : bflo(u1);
            p2 = (oc & 1) ? bfhi(u2) : bflo(u2);
            p3 = (oc & 1) ? bfhi(u3) : bflo(u3);
        }
        r.x = fmaxf(fmaf(p0, sc[oc], sh[oc]) + xv.x, 0.f);
        r.y = fmaxf(fmaf(p1, sc[oc], sh[oc]) + xv.y, 0.f);
        r.z = fmaxf(fmaf(p2, sc[oc], sh[oc]) + xv.z, 0.f);
        r.w = fmaxf(fmaf(p3, sc[oc], sh[oc]) + xv.w, 0.f);
        __builtin_nontemporal_store(r, (f4nt*)(ob + (size_t)oc * HWX));
    }
}

extern "C" void kernel_launch(void* const* d_in, const int* in_sizes, int n_in,
                              void* d_out, int out_size, void* d_ws, size_t ws_size,
                              hipStream_t stream)
{
    const float* x     = (const float*)d_in[0];
    const float* tm_w  = (const float*)d_in[1];
    const float* tm_b  = (const float*)d_in[2];
    const float* dc_w  = (const float*)d_in[3];
    const float* gamma = (const float*)d_in[4];
    const float* beta  = (const float*)d_in[5];
    float* out = (float*)d_out;

    float* ws = (float*)d_ws;
    float* stat_sum = ws;                          // 272
    float* stat_sqs = ws + CC;                     // 272
    unsigned* dc_wh = (unsigned*)(ws + 2048);      // 19584 u32 (half2 deform weights)
    unsigned* tm_wh = dc_wh + 19712;               // 7344 u32 (half2 aff weights)
    float* aff = (float*)(tm_wh + 7424);           // 3,342,336 floats
    unsigned* xtb = (unsigned*)(aff + (size_t)BB * AFFC * HWX);      // f16 xt, 2 planes
    unsigned* preb = xtb + 2 * PSTR;                                 // bf16 pre

    (void)hipMemsetAsync(stat_sum, 0, 2 * CC * sizeof(float), stream);

    wt_kernel<<<dim3(77), dim3(256), 0, stream>>>(dc_w, tm_w, dc_wh, tm_wh);
    transpose_kernel<<<dim3(BB * GG * HH), dim3(256), 0, stream>>>(x, xtb);
    aff_conv_kernel<<<dim3(HWX / 256, GG, BB), dim3(256), 0, stream>>>(xtb, tm_wh, tm_b, aff);
    deform_kernel<<<dim3(NWG), dim3(16, 16), 0, stream>>>(
        xtb, dc_wh, aff, preb, stat_sum, stat_sqs);
    bn_res_relu_kernel<<<dim3(NSLAB * 16), dim3(256), 0, stream>>>(
        preb, x, stat_sum, stat_sqs, gamma, beta, out);
}

// Round 17
// 121.318 us; speedup vs baseline: 1.1687x; 1.1687x over previous
//
#include <hip/hip_runtime.h>
#include <math.h>

#define BB 2
#define CC 272
#define GG 17
#define CG 16
#define HH 128
#define WW 128
#define HWX (HH*WW)
#define AFFC 102   // 6*G
#define NSLAB (BB*GG)          // 34
#define TILES_PER_SLAB 64      // (128/16)^2
#define NWG (NSLAB*TILES_PER_SLAB)  // 2176 = 8*272
#define WGPX (NWG/8)           // 272 per XCD
#define PSTR ((size_t)NSLAB*HWX*4)  // u32 stride between the two 8-ch planes

typedef float f4nt __attribute__((ext_vector_type(4)));     // NT-compatible vec4
typedef float f2nt __attribute__((ext_vector_type(2)));     // NT-compatible vec2
typedef unsigned u4nt __attribute__((ext_vector_type(4)));  // NT-compatible uvec4
typedef _Float16 h2 __attribute__((ext_vector_type(2)));    // packed half2

__device__ __forceinline__ h2 bch(unsigned u) { return __builtin_bit_cast(h2, u); }
__device__ __forceinline__ unsigned hpk(float a, float b) {
    return __builtin_bit_cast(unsigned, __builtin_amdgcn_cvt_pkrtz(a, b));
}
__device__ __forceinline__ h2 hbc(float a) {
    return __builtin_bit_cast(h2, __builtin_amdgcn_cvt_pkrtz(a, a));
}

#if __has_builtin(__builtin_amdgcn_fdot2)
#define FDOT2(A, B, C) __builtin_amdgcn_fdot2((A), (B), (C), false)
#else
#define FDOT2(A, B, C) fmaf((float)(A).x, (float)(B).x, fmaf((float)(A).y, (float)(B).y, (C)))
#endif

// bf16 helpers (pre-BN staging stays bf16)
__device__ __forceinline__ unsigned f2bf(float f) {
    unsigned u = __float_as_uint(f);
    return (u + 0x7fffu + ((u >> 16) & 1u)) >> 16;
}
__device__ __forceinline__ float bflo(unsigned u) { return __uint_as_float(u << 16); }
__device__ __forceinline__ float bfhi(unsigned u) { return __uint_as_float(u & 0xffff0000u); }

// ---------------- Kernel W: weight re-layouts to packed half2 ---------------
__global__ __launch_bounds__(256) void wt_kernel(
    const float* __restrict__ dc_w, const float* __restrict__ tm_w,
    unsigned* __restrict__ dc_wh, unsigned* __restrict__ tm_wh)
{
    int i = blockIdx.x * 256 + threadIdx.x;
    if (i < GG * 8 * 9 * CG) {           // 19584
        int oc = i & 15, t = (i >> 4) % 9, cp = (i / 144) % 8, g = i / 1152;
        float w0 = dc_w[((size_t)(g * 16 + oc) * 16 + 2 * cp) * 9 + t];
        float w1 = dc_w[((size_t)(g * 16 + oc) * 16 + 2 * cp + 1) * 9 + t];
        dc_wh[i] = hpk(w0, w1);
    }
    if (i < GG * 6 * 9 * 8) {            // 7344
        int cp = i & 7, t = (i >> 3) % 9, j = (i / 72) % 6, ig = i / 432;
        float w0 = tm_w[((size_t)(ig * 6 + j) * 16 + 2 * cp) * 9 + t];
        float w1 = tm_w[((size_t)(ig * 6 + j) * 16 + 2 * cp + 1) * 9 + t];
        tm_wh[i] = hpk(w0, w1);
    }
}

// ------- Kernel T: NCHW -> two 8-channel planes, f16, 16B/px per plane ------
__global__ __launch_bounds__(256) void transpose_kernel(
    const float* __restrict__ x, unsigned* __restrict__ xt)
{
    __shared__ float tile[CG][WW + 1];
    const int h = blockIdx.x & (HH - 1);
    const int g = (blockIdx.x >> 7) % GG;
    const int b = blockIdx.x / (GG * HH);
    const int tid = threadIdx.x;
    const float* src = x + (size_t)(b * CC + g * CG) * HWX + h * WW;
    for (int i = tid; i < CG * WW; i += 256) {
        int c = i >> 7, w = i & (WW - 1);
        tile[c][w] = src[(size_t)c * HWX + w];
    }
    __syncthreads();
    const size_t rowbase = ((size_t)(b * GG + g) * HWX + h * WW) * 4;
    unsigned* d0 = xt + rowbase;          // plane0
    unsigned* d1 = xt + PSTR + rowbase;   // plane1
    for (int i = tid; i < 4 * WW; i += 256) {
        int w = i >> 2, c4 = i & 3;       // u32 c4 of px w
        d0[(size_t)w * 4 + c4] = hpk(tile[2 * c4][w],     tile[2 * c4 + 1][w]);
        d1[(size_t)w * 4 + c4] = hpk(tile[8 + 2 * c4][w], tile[8 + 2 * c4 + 1][w]);
    }
}

// ---------------- Kernel A: grouped 3x3 offset-transform conv ----------------
// unroll 1 on taps (R11 lesson). Output scattered into packed layout
// aff2[b][g'][px][6]: channel o = ig*6+j -> i=o/51, rem=o%51, j2=rem/17,
// g'=rem%17, e=i*3+j2 (all block-uniform scalar math).
__global__ __launch_bounds__(256) void aff_conv_kernel(
    const unsigned* __restrict__ xt, const unsigned* __restrict__ tm_wh,
    const float* __restrict__ tm_b, float* __restrict__ aff2)
{
    const int ig = blockIdx.y;
    const int b = blockIdx.z;
    const int tid = threadIdx.x;

    const int p = blockIdx.x * 256 + tid;
    const int h = p >> 7, w = p & (WW - 1);
    const unsigned* xb0 = xt + (size_t)(b * GG + ig) * HWX * 4;
    const unsigned* xb1 = xb0 + PSTR;
    const unsigned* wbh = tm_wh + (size_t)ig * (6 * 9 * 8);   // [j][t][cp]

    float acc[6];
#pragma unroll
    for (int j = 0; j < 6; ++j) acc[j] = 0.f;

#pragma unroll 1
    for (int t = 0; t < 9; ++t) {
        int hy = h + t / 3 - 1;
        int wx = w + t % 3 - 1;
        uint4 u0 = {0, 0, 0, 0}, u1 = {0, 0, 0, 0};
        if (hy >= 0 && hy < HH && wx >= 0 && wx < WW) {
            u0 = *(const uint4*)(xb0 + (size_t)(hy * WW + wx) * 4);
            u1 = *(const uint4*)(xb1 + (size_t)(hy * WW + wx) * 4);
        }
#pragma unroll
        for (int j = 0; j < 6; ++j) {
            const uint4* wp = (const uint4*)(wbh + (j * 9 + t) * 8);  // uniform -> s_load
            uint4 qa = wp[0], qb = wp[1];
            float a = acc[j];
            a = FDOT2(bch(u0.x), bch(qa.x), a); a = FDOT2(bch(u0.y), bch(qa.y), a);
            a = FDOT2(bch(u0.z), bch(qa.z), a); a = FDOT2(bch(u0.w), bch(qa.w), a);
            a = FDOT2(bch(u1.x), bch(qb.x), a); a = FDOT2(bch(u1.y), bch(qb.y), a);
            a = FDOT2(bch(u1.z), bch(qb.z), a); a = FDOT2(bch(u1.w), bch(qb.w), a);
            acc[j] = a;
        }
    }
#pragma unroll
    for (int j = 0; j < 6; ++j) {
        int o = ig * 6 + j;                 // conv output channel
        int i_ = o / 51, rem = o % 51;
        int j2 = rem / 17, gp = rem % 17;   // consumer (row-of-A, deform group)
        int e = i_ * 3 + j2;
        aff2[((size_t)(b * GG + gp) * HWX + p) * 6 + e] = acc[j] + tm_b[o];
    }
}

// ---------------- Kernel C: deformable grouped conv + BN-stat partials -------
// 1D grid, XCD-chunked; two-plane f16 xt; packed-half2 bilinear; fdot2 MAC.
// aff2 packed [px][6] -> 3 contiguous 8B NT loads (was 6 plane-scattered).
// launch_bounds (256,6): VGPR lands 40, NO SPILL -- empirically best. (256,8)
// spills (R10); no bound -> VGPR 64, occupancy collapse (R16). DO NOT TOUCH.

#define MACC(T, CP, S2) { \
    const uint4* wp_ = (const uint4*)(wgh + ((CP) * 9 + (T)) * CG); \
    uint4 q0 = wp_[0], q1 = wp_[1], q2 = wp_[2], q3 = wp_[3]; \
    acc[0]  = FDOT2(S2, bch(q0.x), acc[0]);  acc[1]  = FDOT2(S2, bch(q0.y), acc[1]); \
    acc[2]  = FDOT2(S2, bch(q0.z), acc[2]);  acc[3]  = FDOT2(S2, bch(q0.w), acc[3]); \
    acc[4]  = FDOT2(S2, bch(q1.x), acc[4]);  acc[5]  = FDOT2(S2, bch(q1.y), acc[5]); \
    acc[6]  = FDOT2(S2, bch(q1.z), acc[6]);  acc[7]  = FDOT2(S2, bch(q1.w), acc[7]); \
    acc[8]  = FDOT2(S2, bch(q2.x), acc[8]);  acc[9]  = FDOT2(S2, bch(q2.y), acc[9]); \
    acc[10] = FDOT2(S2, bch(q2.z), acc[10]); acc[11] = FDOT2(S2, bch(q2.w), acc[11]); \
    acc[12] = FDOT2(S2, bch(q3.x), acc[12]); acc[13] = FDOT2(S2, bch(q3.y), acc[13]); \
    acc[14] = FDOT2(S2, bch(q3.z), acc[14]); acc[15] = FDOT2(S2, bch(q3.w), acc[15]); }

#define SEM(T, CP, UA, UB, UC, UD) { \
    h2 s2 = bch(UA) * W00 + bch(UB) * W01 + bch(UC) * W10 + bch(UD) * W11; \
    MACC(T, CP, s2) }

#define TAP(T, I0, K0, I1, K1) { \
    float dy = ((I0) ? a10 : a00) * (float)((K0) / 3 - 1) \
             + ((I0) ? a11 : a01) * (float)((K0) % 3 - 1) + ((I0) ? a12 : a02); \
    float dx = ((I1) ? a10 : a00) * (float)((K1) / 3 - 1) \
             + ((I1) ? a11 : a01) * (float)((K1) % 3 - 1) + ((I1) ? a12 : a02); \
    float py = (float)(h + (T) / 3 - 1) + dy; \
    float px = (float)(w + (T) % 3 - 1) + dx; \
    float y0f = floorf(py), x0f = floorf(px); \
    float wy = py - y0f, wx = px - x0f; \
    int y0 = (int)y0f, x0 = (int)x0f; \
    int y1 = y0 + 1, x1 = x0 + 1; \
    bool vy0 = (y0 >= 0) && (y0 < HH), vy1 = (y1 >= 0) && (y1 < HH); \
    bool vx0 = (x0 >= 0) && (x0 < WW), vx1 = (x1 >= 0) && (x1 < WW); \
    int y0c = min(max(y0, 0), HH - 1), y1c = min(max(y1, 0), HH - 1); \
    int x0c = min(max(x0, 0), WW - 1), x1c = min(max(x1, 0), WW - 1); \
    float w00 = (vy0 && vx0) ? (1.f - wy) * (1.f - wx) : 0.f; \
    float w01 = (vy0 && vx1) ? (1.f - wy) * wx : 0.f; \
    float w10 = (vy1 && vx0) ? wy * (1.f - wx) : 0.f; \
    float w11 = (vy1 && vx1) ? wy * wx : 0.f; \
    h2 W00 = hbc(w00), W01 = hbc(w01), W10 = hbc(w10), W11 = hbc(w11); \
    int l00 = y0c * WW + x0c, l01 = y0c * WW + x1c; \
    int l10 = y1c * WW + x0c, l11 = y1c * WW + x1c; \
    uint4 A0 = *(const uint4*)(xb0 + (size_t)l00 * 4); \
    uint4 A1 = *(const uint4*)(xb1 + (size_t)l00 * 4); \
    uint4 B0 = *(const uint4*)(xb0 + (size_t)l01 * 4); \
    uint4 B1 = *(const uint4*)(xb1 + (size_t)l01 * 4); \
    uint4 C0 = *(const uint4*)(xb0 + (size_t)l10 * 4); \
    uint4 C1 = *(const uint4*)(xb1 + (size_t)l10 * 4); \
    uint4 D0 = *(const uint4*)(xb0 + (size_t)l11 * 4); \
    uint4 D1 = *(const uint4*)(xb1 + (size_t)l11 * 4); \
    SEM(T, 0, A0.x, B0.x, C0.x, D0.x) SEM(T, 1, A0.y, B0.y, C0.y, D0.y) \
    SEM(T, 2, A0.z, B0.z, C0.z, D0.z) SEM(T, 3, A0.w, B0.w, C0.w, D0.w) \
    SEM(T, 4, A1.x, B1.x, C1.x, D1.x) SEM(T, 5, A1.y, B1.y, C1.y, D1.y) \
    SEM(T, 6, A1.z, B1.z, C1.z, D1.z) SEM(T, 7, A1.w, B1.w, C1.w, D1.w) }

__global__ __launch_bounds__(256, 6) void deform_kernel(
    const unsigned* __restrict__ xt, const unsigned* __restrict__ dc_wh,
    const float* __restrict__ aff2, unsigned* __restrict__ pre,
    float* __restrict__ stat_sum, float* __restrict__ stat_sqs)
{
    __shared__ float red[CG][4][2];

    const int bid = blockIdx.x;
    const int work = (bid & 7) * WGPX + (bid >> 3);
    const int slab = work / TILES_PER_SLAB;      // (b,g)
    const int tile = work % TILES_PER_SLAB;
    const int b = slab / GG;
    const int g = slab % GG;

    const int tid = threadIdx.y * 16 + threadIdx.x;
    const int h = (tile >> 3) * 16 + threadIdx.y;
    const int w = (tile & 7) * 16 + threadIdx.x;

    // packed 2x3 affine params: 3 contiguous 8B NT loads
    const float* ap = aff2 + ((size_t)(b * GG + g) * HWX + h * WW + w) * 6;
    f2nt v0 = __builtin_nontemporal_load((const f2nt*)ap);
    f2nt v1 = __builtin_nontemporal_load((const f2nt*)(ap + 2));
    f2nt v2 = __builtin_nontemporal_load((const f2nt*)(ap + 4));
    float a00 = v0.x, a01 = v0.y, a02 = v1.x;
    float a10 = v1.y, a11 = v2.x, a12 = v2.y;

    const unsigned* xb0 = xt + (size_t)(b * GG + g) * HWX * 4;
    const unsigned* xb1 = xb0 + PSTR;
    const unsigned* wgh = dc_wh + (size_t)g * (8 * 9 * CG);   // [cp][t][oc]

    float acc[CG];
#pragma unroll
    for (int oc = 0; oc < CG; ++oc) acc[oc] = 0.f;

    // flat e = i*9+k; tap t: e0=2t -> (I0,K0), e1=2t+1 -> (I1,K1)
    TAP(0, 0, 0, 0, 1)
    TAP(1, 0, 2, 0, 3)
    TAP(2, 0, 4, 0, 5)
    TAP(3, 0, 6, 0, 7)
    TAP(4, 0, 8, 1, 0)
    TAP(5, 1, 1, 1, 2)
    TAP(6, 1, 3, 1, 4)
    TAP(7, 1, 5, 1, 6)
    TAP(8, 1, 7, 1, 8)

    // pre as bf16 channel-last [slab][px][16]: lane writes 32B contiguous (NT)
    unsigned pk[8];
#pragma unroll
    for (int k = 0; k < 8; ++k)
        pk[k] = f2bf(acc[2 * k]) | (f2bf(acc[2 * k + 1]) << 16);
    {
        u4nt q0 = {pk[0], pk[1], pk[2], pk[3]};
        u4nt q1 = {pk[4], pk[5], pk[6], pk[7]};
        u4nt* pp = (u4nt*)(pre + ((size_t)slab * HWX + h * WW + w) * (CG / 2));
        __builtin_nontemporal_store(q0, pp);
        __builtin_nontemporal_store(q1, pp + 1);
    }

    // BN partial sums from exact f32 acc
    const int lane = tid & 63, wave = tid >> 6;
#pragma unroll
    for (int oc = 0; oc < CG; ++oc) {
        float s = acc[oc], q = acc[oc] * acc[oc];
#pragma unroll
        for (int off = 32; off > 0; off >>= 1) {
            s += __shfl_down(s, off);
            q += __shfl_down(q, off);
        }
        if (lane == 0) { red[oc][wave][0] = s; red[oc][wave][1] = q; }
    }
    __syncthreads();
    if (tid < CG) {
        float s = red[tid][0][0] + red[tid][1][0] + red[tid][2][0] + red[tid][3][0];
        float q = red[tid][0][1] + red[tid][1][1] + red[tid][2][1] + red[tid][3][1];
        int ch = g * CG + tid;
        atomicAdd(&stat_sum[ch], s);
        atomicAdd(&stat_sqs[ch], q);
    }
}

// ---------------- Kernel D: BN + residual ReLU (pre: bf16 channel-last) ------
__global__ __launch_bounds__(256) void bn_res_relu_kernel(
    const unsigned* __restrict__ pre, const float* __restrict__ x,
    const float* __restrict__ ssum, const float* __restrict__ ssqs,
    const float* __restrict__ gamma, const float* __restrict__ beta,
    float* __restrict__ out)
{
    const int blk = blockIdx.x;
    const int slab = blk >> 4;       // 16 chunks per slab
    const int chunk = blk & 15;
    const int b = slab / GG, g = slab % GG;
    const int px0 = chunk * 1024 + threadIdx.x * 4;

    const float n = (float)(BB * HWX);
    float sc[16], sh[16];
#pragma unroll
    for (int oc = 0; oc < 16; ++oc) {
        int ch = g * CG + oc;
        float mean = ssum[ch] / n;
        float var = ssqs[ch] / n - mean * mean;
        float s = rsqrtf(var + 1e-5f) * gamma[ch];
        sc[oc] = s;
        sh[oc] = fmaf(-mean, s, beta[ch]);
    }

    const uint4* pp = (const uint4*)(pre + ((size_t)slab * HWX + px0) * (CG / 2));
    unsigned Pu[32];
#pragma unroll
    for (int k = 0; k < 8; ++k) {
        uint4 v = pp[k];
        Pu[4 * k] = v.x; Pu[4 * k + 1] = v.y; Pu[4 * k + 2] = v.z; Pu[4 * k + 3] = v.w;
    }
    const float* xb = x + (size_t)(b * CC + g * CG) * HWX + px0;
    float* ob = out + (size_t)(b * CC + g * CG) * HWX + px0;

#pragma unroll
    for (int oc = 0; oc < 16; ++oc) {
        f4nt xv = __builtin_nontemporal_load((const f4nt*)(xb + (size_t)oc * HWX));
        f4nt r;
        float p0, p1, p2, p3;
        {
            unsigned u0 = Pu[0 * 8 + (oc >> 1)], u1 = Pu[1 * 8 + (oc >> 1)];
            unsigned u2 = Pu[2 * 8 + (oc >> 1)], u3 = Pu[3 * 8 + (oc >> 1)];
            p0 = (oc & 1) ? bfhi(u0) : bflo(u0);
            p1 = (oc & 1) ? bfhi(u1) : bflo(u1);
            p2 = (oc & 1) ? bfhi(u2) : bflo(u2);
            p3 = (oc & 1) ? bfhi(u3) : bflo(u3);
        }
        r.x = fmaxf(fmaf(p0, sc[oc], sh[oc]) + xv.x, 0.f);
        r.y = fmaxf(fmaf(p1, sc[oc], sh[oc]) + xv.y, 0.f);
        r.z = fmaxf(fmaf(p2, sc[oc], sh[oc]) + xv.z, 0.f);
        r.w = fmaxf(fmaf(p3, sc[oc], sh[oc]) + xv.w, 0.f);
        __builtin_nontemporal_store(r, (f4nt*)(ob + (size_t)oc * HWX));
    }
}

extern "C" void kernel_launch(void* const* d_in, const int* in_sizes, int n_in,
                              void* d_out, int out_size, void* d_ws, size_t ws_size,
                              hipStream_t stream)
{
    const float* x     = (const float*)d_in[0];
    const float* tm_w  = (const float*)d_in[1];
    const float* tm_b  = (const float*)d_in[2];
    const float* dc_w  = (const float*)d_in[3];
    const float* gamma = (const float*)d_in[4];
    const float* beta  = (const float*)d_in[5];
    float* out = (float*)d_out;

    float* ws = (float*)d_ws;
    float* stat_sum = ws;                          // 272
    float* stat_sqs = ws + CC;                     // 272
    unsigned* dc_wh = (unsigned*)(ws + 2048);      // 19584 u32 (half2 deform weights)
    unsigned* tm_wh = dc_wh + 19712;               // 7344 u32 (half2 aff weights)
    float* aff2 = (float*)(tm_wh + 7424);          // 3,342,336 floats, [b][g'][px][6]
    unsigned* xtb = (unsigned*)(aff2 + (size_t)BB * GG * HWX * 6);   // f16 xt, 2 planes
    unsigned* preb = xtb + 2 * PSTR;                                 // bf16 pre

    (void)hipMemsetAsync(stat_sum, 0, 2 * CC * sizeof(float), stream);

    wt_kernel<<<dim3(77), dim3(256), 0, stream>>>(dc_w, tm_w, dc_wh, tm_wh);
    transpose_kernel<<<dim3(BB * GG * HH), dim3(256), 0, stream>>>(x, xtb);
    aff_conv_kernel<<<dim3(HWX / 256, GG, BB), dim3(256), 0, stream>>>(xtb, tm_wh, tm_b, aff2);
    deform_kernel<<<dim3(NWG), dim3(16, 16), 0, stream>>>(
        xtb, dc_wh, aff2, preb, stat_sum, stat_sqs);
    bn_res_relu_kernel<<<dim3(NSLAB * 16), dim3(256), 0, stream>>>(
        preb, x, stat_sum, stat_sqs, gamma, beta, out);
}

// Round 18
// 119.548 us; speedup vs baseline: 1.1860x; 1.0148x over previous
//
#include <hip/hip_runtime.h>
#include <math.h>

#define BB 2
#define CC 272
#define GG 17
#define CG 16
#define HH 128
#define WW 128
#define HWX (HH*WW)
#define AFFC 102   // 6*G
#define NSLAB (BB*GG)          // 34
#define TILES_PER_SLAB 128     // 8 x-tiles (16 wide) * 16 y-tiles (8 tall)
#define NWG (NSLAB*TILES_PER_SLAB)  // 4352 = 8*544
#define WGPX (NWG/8)           // 544 per XCD
#define PSTR ((size_t)NSLAB*HWX*4)  // u32 stride between the two 8-ch planes

typedef float f4nt __attribute__((ext_vector_type(4)));     // NT-compatible vec4
typedef float f2nt __attribute__((ext_vector_type(2)));     // NT-compatible vec2
typedef unsigned u4nt __attribute__((ext_vector_type(4)));  // NT-compatible uvec4
typedef _Float16 h2 __attribute__((ext_vector_type(2)));    // packed half2

__device__ __forceinline__ h2 bch(unsigned u) { return __builtin_bit_cast(h2, u); }
__device__ __forceinline__ unsigned hpk(float a, float b) {
    return __builtin_bit_cast(unsigned, __builtin_amdgcn_cvt_pkrtz(a, b));
}
__device__ __forceinline__ h2 hbc(float a) {
    return __builtin_bit_cast(h2, __builtin_amdgcn_cvt_pkrtz(a, a));
}

#if __has_builtin(__builtin_amdgcn_fdot2)
#define FDOT2(A, B, C) __builtin_amdgcn_fdot2((A), (B), (C), false)
#else
#define FDOT2(A, B, C) fmaf((float)(A).x, (float)(B).x, fmaf((float)(A).y, (float)(B).y, (C)))
#endif

// bf16 helpers (pre-BN staging stays bf16)
__device__ __forceinline__ unsigned f2bf(float f) {
    unsigned u = __float_as_uint(f);
    return (u + 0x7fffu + ((u >> 16) & 1u)) >> 16;
}
__device__ __forceinline__ float bflo(unsigned u) { return __uint_as_float(u << 16); }
__device__ __forceinline__ float bfhi(unsigned u) { return __uint_as_float(u & 0xffff0000u); }

// ---------------- Kernel W: weight re-layouts to packed half2 ---------------
__global__ __launch_bounds__(256) void wt_kernel(
    const float* __restrict__ dc_w, const float* __restrict__ tm_w,
    unsigned* __restrict__ dc_wh, unsigned* __restrict__ tm_wh)
{
    int i = blockIdx.x * 256 + threadIdx.x;
    if (i < GG * 8 * 9 * CG) {           // 19584
        int oc = i & 15, t = (i >> 4) % 9, cp = (i / 144) % 8, g = i / 1152;
        float w0 = dc_w[((size_t)(g * 16 + oc) * 16 + 2 * cp) * 9 + t];
        float w1 = dc_w[((size_t)(g * 16 + oc) * 16 + 2 * cp + 1) * 9 + t];
        dc_wh[i] = hpk(w0, w1);
    }
    if (i < GG * 6 * 9 * 8) {            // 7344
        int cp = i & 7, t = (i >> 3) % 9, j = (i / 72) % 6, ig = i / 432;
        float w0 = tm_w[((size_t)(ig * 6 + j) * 16 + 2 * cp) * 9 + t];
        float w1 = tm_w[((size_t)(ig * 6 + j) * 16 + 2 * cp + 1) * 9 + t];
        tm_wh[i] = hpk(w0, w1);
    }
}

// ------- Kernel T: NCHW -> two 8-channel planes, f16, 16B/px per plane ------
__global__ __launch_bounds__(256) void transpose_kernel(
    const float* __restrict__ x, unsigned* __restrict__ xt)
{
    __shared__ float tile[CG][WW + 1];
    const int h = blockIdx.x & (HH - 1);
    const int g = (blockIdx.x >> 7) % GG;
    const int b = blockIdx.x / (GG * HH);
    const int tid = threadIdx.x;
    const float* src = x + (size_t)(b * CC + g * CG) * HWX + h * WW;
    for (int i = tid; i < CG * WW; i += 256) {
        int c = i >> 7, w = i & (WW - 1);
        tile[c][w] = src[(size_t)c * HWX + w];
    }
    __syncthreads();
    const size_t rowbase = ((size_t)(b * GG + g) * HWX + h * WW) * 4;
    unsigned* d0 = xt + rowbase;          // plane0
    unsigned* d1 = xt + PSTR + rowbase;   // plane1
    for (int i = tid; i < 4 * WW; i += 256) {
        int w = i >> 2, c4 = i & 3;       // u32 c4 of px w
        d0[(size_t)w * 4 + c4] = hpk(tile[2 * c4][w],     tile[2 * c4 + 1][w]);
        d1[(size_t)w * 4 + c4] = hpk(tile[8 + 2 * c4][w], tile[8 + 2 * c4 + 1][w]);
    }
}

// ---------------- Kernel A: grouped 3x3 offset-transform conv ----------------
// 128-thread blocks (4352 wgs) for smoother residency/tail. unroll 1 on taps
// (R11 lesson). Output packed aff2[b][g'][px][6].
__global__ __launch_bounds__(128) void aff_conv_kernel(
    const unsigned* __restrict__ xt, const unsigned* __restrict__ tm_wh,
    const float* __restrict__ tm_b, float* __restrict__ aff2)
{
    const int ig = blockIdx.y;
    const int b = blockIdx.z;
    const int tid = threadIdx.x;

    const int p = blockIdx.x * 128 + tid;
    const int h = p >> 7, w = p & (WW - 1);
    const unsigned* xb0 = xt + (size_t)(b * GG + ig) * HWX * 4;
    const unsigned* xb1 = xb0 + PSTR;
    const unsigned* wbh = tm_wh + (size_t)ig * (6 * 9 * 8);   // [j][t][cp]

    float acc[6];
#pragma unroll
    for (int j = 0; j < 6; ++j) acc[j] = 0.f;

#pragma unroll 1
    for (int t = 0; t < 9; ++t) {
        int hy = h + t / 3 - 1;
        int wx = w + t % 3 - 1;
        uint4 u0 = {0, 0, 0, 0}, u1 = {0, 0, 0, 0};
        if (hy >= 0 && hy < HH && wx >= 0 && wx < WW) {
            u0 = *(const uint4*)(xb0 + (size_t)(hy * WW + wx) * 4);
            u1 = *(const uint4*)(xb1 + (size_t)(hy * WW + wx) * 4);
        }
#pragma unroll
        for (int j = 0; j < 6; ++j) {
            const uint4* wp = (const uint4*)(wbh + (j * 9 + t) * 8);  // uniform -> s_load
            uint4 qa = wp[0], qb = wp[1];
            float a = acc[j];
            a = FDOT2(bch(u0.x), bch(qa.x), a); a = FDOT2(bch(u0.y), bch(qa.y), a);
            a = FDOT2(bch(u0.z), bch(qa.z), a); a = FDOT2(bch(u0.w), bch(qa.w), a);
            a = FDOT2(bch(u1.x), bch(qb.x), a); a = FDOT2(bch(u1.y), bch(qb.y), a);
            a = FDOT2(bch(u1.z), bch(qb.z), a); a = FDOT2(bch(u1.w), bch(qb.w), a);
            acc[j] = a;
        }
    }
#pragma unroll
    for (int j = 0; j < 6; ++j) {
        int o = ig * 6 + j;                 // conv output channel
        int i_ = o / 51, rem = o % 51;
        int j2 = rem / 17, gp = rem % 17;   // consumer (row-of-A, deform group)
        int e = i_ * 3 + j2;
        aff2[((size_t)(b * GG + gp) * HWX + p) * 6 + e] = acc[j] + tm_b[o];
    }
}

// ---------------- Kernel C: deformable grouped conv + BN-stat partials -------
// 128-thread blocks, 16x8 tiles (4352 wgs = 8*544, XCD-chunked): finer
// granularity smooths residency ramp/tail (R17 diagnosis: grid 2176 = only
// 8.5 blocks/CU total -> tail dominated). launch_bounds (128,6): same 85-VGPR
// cap as (256,6) -> VGPR 40, NO SPILL; 12 blocks/CU legal.
// (256,8)-style forced 32-VGPR fit spills (R10). DO NOT force lower.

#define MACC(T, CP, S2) { \
    const uint4* wp_ = (const uint4*)(wgh + ((CP) * 9 + (T)) * CG); \
    uint4 q0 = wp_[0], q1 = wp_[1], q2 = wp_[2], q3 = wp_[3]; \
    acc[0]  = FDOT2(S2, bch(q0.x), acc[0]);  acc[1]  = FDOT2(S2, bch(q0.y), acc[1]); \
    acc[2]  = FDOT2(S2, bch(q0.z), acc[2]);  acc[3]  = FDOT2(S2, bch(q0.w), acc[3]); \
    acc[4]  = FDOT2(S2, bch(q1.x), acc[4]);  acc[5]  = FDOT2(S2, bch(q1.y), acc[5]); \
    acc[6]  = FDOT2(S2, bch(q1.z), acc[6]);  acc[7]  = FDOT2(S2, bch(q1.w), acc[7]); \
    acc[8]  = FDOT2(S2, bch(q2.x), acc[8]);  acc[9]  = FDOT2(S2, bch(q2.y), acc[9]); \
    acc[10] = FDOT2(S2, bch(q2.z), acc[10]); acc[11] = FDOT2(S2, bch(q2.w), acc[11]); \
    acc[12] = FDOT2(S2, bch(q3.x), acc[12]); acc[13] = FDOT2(S2, bch(q3.y), acc[13]); \
    acc[14] = FDOT2(S2, bch(q3.z), acc[14]); acc[15] = FDOT2(S2, bch(q3.w), acc[15]); }

#define SEM(T, CP, UA, UB, UC, UD) { \
    h2 s2 = bch(UA) * W00 + bch(UB) * W01 + bch(UC) * W10 + bch(UD) * W11; \
    MACC(T, CP, s2) }

#define TAP(T, I0, K0, I1, K1) { \
    float dy = ((I0) ? a10 : a00) * (float)((K0) / 3 - 1) \
             + ((I0) ? a11 : a01) * (float)((K0) % 3 - 1) + ((I0) ? a12 : a02); \
    float dx = ((I1) ? a10 : a00) * (float)((K1) / 3 - 1) \
             + ((I1) ? a11 : a01) * (float)((K1) % 3 - 1) + ((I1) ? a12 : a02); \
    float py = (float)(h + (T) / 3 - 1) + dy; \
    float px = (float)(w + (T) % 3 - 1) + dx; \
    float y0f = floorf(py), x0f = floorf(px); \
    float wy = py - y0f, wx = px - x0f; \
    int y0 = (int)y0f, x0 = (int)x0f; \
    int y1 = y0 + 1, x1 = x0 + 1; \
    bool vy0 = (y0 >= 0) && (y0 < HH), vy1 = (y1 >= 0) && (y1 < HH); \
    bool vx0 = (x0 >= 0) && (x0 < WW), vx1 = (x1 >= 0) && (x1 < WW); \
    int y0c = min(max(y0, 0), HH - 1), y1c = min(max(y1, 0), HH - 1); \
    int x0c = min(max(x0, 0), WW - 1), x1c = min(max(x1, 0), WW - 1); \
    float w00 = (vy0 && vx0) ? (1.f - wy) * (1.f - wx) : 0.f; \
    float w01 = (vy0 && vx1) ? (1.f - wy) * wx : 0.f; \
    float w10 = (vy1 && vx0) ? wy * (1.f - wx) : 0.f; \
    float w11 = (vy1 && vx1) ? wy * wx : 0.f; \
    h2 W00 = hbc(w00), W01 = hbc(w01), W10 = hbc(w10), W11 = hbc(w11); \
    int l00 = y0c * WW + x0c, l01 = y0c * WW + x1c; \
    int l10 = y1c * WW + x0c, l11 = y1c * WW + x1c; \
    uint4 A0 = *(const uint4*)(xb0 + (size_t)l00 * 4); \
    uint4 A1 = *(const uint4*)(xb1 + (size_t)l00 * 4); \
    uint4 B0 = *(const uint4*)(xb0 + (size_t)l01 * 4); \
    uint4 B1 = *(const uint4*)(xb1 + (size_t)l01 * 4); \
    uint4 C0 = *(const uint4*)(xb0 + (size_t)l10 * 4); \
    uint4 C1 = *(const uint4*)(xb1 + (size_t)l10 * 4); \
    uint4 D0 = *(const uint4*)(xb0 + (size_t)l11 * 4); \
    uint4 D1 = *(const uint4*)(xb1 + (size_t)l11 * 4); \
    SEM(T, 0, A0.x, B0.x, C0.x, D0.x) SEM(T, 1, A0.y, B0.y, C0.y, D0.y) \
    SEM(T, 2, A0.z, B0.z, C0.z, D0.z) SEM(T, 3, A0.w, B0.w, C0.w, D0.w) \
    SEM(T, 4, A1.x, B1.x, C1.x, D1.x) SEM(T, 5, A1.y, B1.y, C1.y, D1.y) \
    SEM(T, 6, A1.z, B1.z, C1.z, D1.z) SEM(T, 7, A1.w, B1.w, C1.w, D1.w) }

__global__ __launch_bounds__(128, 6) void deform_kernel(
    const unsigned* __restrict__ xt, const unsigned* __restrict__ dc_wh,
    const float* __restrict__ aff2, unsigned* __restrict__ pre,
    float* __restrict__ stat_sum, float* __restrict__ stat_sqs)
{
    __shared__ float red[CG][2][2];

    const int bid = blockIdx.x;
    const int work = (bid & 7) * WGPX + (bid >> 3);
    const int slab = work / TILES_PER_SLAB;      // (b,g)
    const int tile = work % TILES_PER_SLAB;      // 8 x-tiles * 16 y-tiles
    const int b = slab / GG;
    const int g = slab % GG;

    const int tid = threadIdx.y * 16 + threadIdx.x;
    const int h = (tile >> 3) * 8 + threadIdx.y;
    const int w = (tile & 7) * 16 + threadIdx.x;

    // packed 2x3 affine params: 3 contiguous 8B NT loads
    const float* ap = aff2 + ((size_t)(b * GG + g) * HWX + h * WW + w) * 6;
    f2nt v0 = __builtin_nontemporal_load((const f2nt*)ap);
    f2nt v1 = __builtin_nontemporal_load((const f2nt*)(ap + 2));
    f2nt v2 = __builtin_nontemporal_load((const f2nt*)(ap + 4));
    float a00 = v0.x, a01 = v0.y, a02 = v1.x;
    float a10 = v1.y, a11 = v2.x, a12 = v2.y;

    const unsigned* xb0 = xt + (size_t)(b * GG + g) * HWX * 4;
    const unsigned* xb1 = xb0 + PSTR;
    const unsigned* wgh = dc_wh + (size_t)g * (8 * 9 * CG);   // [cp][t][oc]

    float acc[CG];
#pragma unroll
    for (int oc = 0; oc < CG; ++oc) acc[oc] = 0.f;

    // flat e = i*9+k; tap t: e0=2t -> (I0,K0), e1=2t+1 -> (I1,K1)
    TAP(0, 0, 0, 0, 1)
    TAP(1, 0, 2, 0, 3)
    TAP(2, 0, 4, 0, 5)
    TAP(3, 0, 6, 0, 7)
    TAP(4, 0, 8, 1, 0)
    TAP(5, 1, 1, 1, 2)
    TAP(6, 1, 3, 1, 4)
    TAP(7, 1, 5, 1, 6)
    TAP(8, 1, 7, 1, 8)

    // pre as bf16 channel-last [slab][px][16]: lane writes 32B contiguous (NT)
    unsigned pk[8];
#pragma unroll
    for (int k = 0; k < 8; ++k)
        pk[k] = f2bf(acc[2 * k]) | (f2bf(acc[2 * k + 1]) << 16);
    {
        u4nt q0 = {pk[0], pk[1], pk[2], pk[3]};
        u4nt q1 = {pk[4], pk[5], pk[6], pk[7]};
        u4nt* pp = (u4nt*)(pre + ((size_t)slab * HWX + h * WW + w) * (CG / 2));
        __builtin_nontemporal_store(q0, pp);
        __builtin_nontemporal_store(q1, pp + 1);
    }

    // BN partial sums from exact f32 acc (2 waves)
    const int lane = tid & 63, wave = tid >> 6;
#pragma unroll
    for (int oc = 0; oc < CG; ++oc) {
        float s = acc[oc], q = acc[oc] * acc[oc];
#pragma unroll
        for (int off = 32; off > 0; off >>= 1) {
            s += __shfl_down(s, off);
            q += __shfl_down(q, off);
        }
        if (lane == 0) { red[oc][wave][0] = s; red[oc][wave][1] = q; }
    }
    __syncthreads();
    if (tid < CG) {
        float s = red[tid][0][0] + red[tid][1][0];
        float q = red[tid][0][1] + red[tid][1][1];
        int ch = g * CG + tid;
        atomicAdd(&stat_sum[ch], s);
        atomicAdd(&stat_sqs[ch], q);
    }
}

// ---------------- Kernel D: BN + residual ReLU (pre: bf16 channel-last) ------
// 128-thread blocks, 512-px chunks (1088 wgs) for tail smoothing.
__global__ __launch_bounds__(128) void bn_res_relu_kernel(
    const unsigned* __restrict__ pre, const float* __restrict__ x,
    const float* __restrict__ ssum, const float* __restrict__ ssqs,
    const float* __restrict__ gamma, const float* __restrict__ beta,
    float* __restrict__ out)
{
    const int blk = blockIdx.x;
    const int slab = blk >> 5;       // 32 chunks per slab
    const int chunk = blk & 31;
    const int b = slab / GG, g = slab % GG;
    const int px0 = chunk * 512 + threadIdx.x * 4;

    const float n = (float)(BB * HWX);
    float sc[16], sh[16];
#pragma unroll
    for (int oc = 0; oc < 16; ++oc) {
        int ch = g * CG + oc;
        float mean = ssum[ch] / n;
        float var = ssqs[ch] / n - mean * mean;
        float s = rsqrtf(var + 1e-5f) * gamma[ch];
        sc[oc] = s;
        sh[oc] = fmaf(-mean, s, beta[ch]);
    }

    const uint4* pp = (const uint4*)(pre + ((size_t)slab * HWX + px0) * (CG / 2));
    unsigned Pu[32];
#pragma unroll
    for (int k = 0; k < 8; ++k) {
        uint4 v = pp[k];
        Pu[4 * k] = v.x; Pu[4 * k + 1] = v.y; Pu[4 * k + 2] = v.z; Pu[4 * k + 3] = v.w;
    }
    const float* xb = x + (size_t)(b * CC + g * CG) * HWX + px0;
    float* ob = out + (size_t)(b * CC + g * CG) * HWX + px0;

#pragma unroll
    for (int oc = 0; oc < 16; ++oc) {
        f4nt xv = __builtin_nontemporal_load((const f4nt*)(xb + (size_t)oc * HWX));
        f4nt r;
        float p0, p1, p2, p3;
        {
            unsigned u0 = Pu[0 * 8 + (oc >> 1)], u1 = Pu[1 * 8 + (oc >> 1)];
            unsigned u2 = Pu[2 * 8 + (oc >> 1)], u3 = Pu[3 * 8 + (oc >> 1)];
            p0 = (oc & 1) ? bfhi(u0) : bflo(u0);
            p1 = (oc & 1) ? bfhi(u1) : bflo(u1);
            p2 = (oc & 1) ? bfhi(u2) : bflo(u2);
            p3 = (oc & 1) ? bfhi(u3) : bflo(u3);
        }
        r.x = fmaxf(fmaf(p0, sc[oc], sh[oc]) + xv.x, 0.f);
        r.y = fmaxf(fmaf(p1, sc[oc], sh[oc]) + xv.y, 0.f);
        r.z = fmaxf(fmaf(p2, sc[oc], sh[oc]) + xv.z, 0.f);
        r.w = fmaxf(fmaf(p3, sc[oc], sh[oc]) + xv.w, 0.f);
        __builtin_nontemporal_store(r, (f4nt*)(ob + (size_t)oc * HWX));
    }
}

extern "C" void kernel_launch(void* const* d_in, const int* in_sizes, int n_in,
                              void* d_out, int out_size, void* d_ws, size_t ws_size,
                              hipStream_t stream)
{
    const float* x     = (const float*)d_in[0];
    const float* tm_w  = (const float*)d_in[1];
    const float* tm_b  = (const float*)d_in[2];
    const float* dc_w  = (const float*)d_in[3];
    const float* gamma = (const float*)d_in[4];
    const float* beta  = (const float*)d_in[5];
    float* out = (float*)d_out;

    float* ws = (float*)d_ws;
    float* stat_sum = ws;                          // 272
    float* stat_sqs = ws + CC;                     // 272
    unsigned* dc_wh = (unsigned*)(ws + 2048);      // 19584 u32 (half2 deform weights)
    unsigned* tm_wh = dc_wh + 19712;               // 7344 u32 (half2 aff weights)
    float* aff2 = (float*)(tm_wh + 7424);          // 3,342,336 floats, [b][g'][px][6]
    unsigned* xtb = (unsigned*)(aff2 + (size_t)BB * GG * HWX * 6);   // f16 xt, 2 planes
    unsigned* preb = xtb + 2 * PSTR;                                 // bf16 pre

    (void)hipMemsetAsync(stat_sum, 0, 2 * CC * sizeof(float), stream);

    wt_kernel<<<dim3(77), dim3(256), 0, stream>>>(dc_w, tm_w, dc_wh, tm_wh);
    transpose_kernel<<<dim3(BB * GG * HH), dim3(256), 0, stream>>>(x, xtb);
    aff_conv_kernel<<<dim3(HWX / 128, GG, BB), dim3(128), 0, stream>>>(xtb, tm_wh, tm_b, aff2);
    deform_kernel<<<dim3(NWG), dim3(16, 8), 0, stream>>>(
        xtb, dc_wh, aff2, preb, stat_sum, stat_sqs);
    bn_res_relu_kernel<<<dim3(NSLAB * 32), dim3(128), 0, stream>>>(
        preb, x, stat_sum, stat_sqs, gamma, beta, out);
}